// Round 1
// baseline (1699.784 us; speedup 1.0000x reference)
//
#include <hip/hip_runtime.h>
#include <array>

#define DEV_INLINE __device__ __forceinline__

// Problem geometry (fixed by setup_inputs)
constexpr int HH = 512, WW = 512, BB = 4;
constexpr int HWN = HH * WW;
constexpr int OUT1OFF = BB * HWN * 9;   // d_out: [B*HW*9] then [B*HW*13]

// ---------------------------------------------------------------------------
// Compile-time sparse structure of the real Wigner-3j tensors.
// Support rule (exact): |u3| in {|u1|+|u2|, ||u1|-|u2||} and an even number of
// negative (sin-type) indices.  (q-matrix sin-columns are purely imaginary,
// cos-columns purely real -> odd-negative entries have zero real part.)
// ---------------------------------------------------------------------------
constexpr bool keepE(int u1, int u2, int u3) {
    int a = u1 < 0 ? -u1 : u1, b = u2 < 0 ? -u2 : u2, c = u3 < 0 ? -u3 : u3;
    int neg = (u1 < 0) + (u2 < 0) + (u3 < 0);
    if (neg & 1) return false;
    int d = a > b ? a - b : b - a;
    return (c == a + b) || (c == d);
}

struct Ent { unsigned char xi, yi, oi, p; };

constexpr int GRP[4][2] = {{4,4},{4,6},{6,4},{6,6}};

constexpr int countEnt() {
    int n = 0;
    for (int g = 0; g < 4; ++g) {
        int l1 = GRP[g][0], l2 = GRP[g][1];
        for (int u1 = -l1; u1 <= l1; ++u1)
            for (int u2 = -l2; u2 <= l2; ++u2)
                for (int t3 = 0; t3 < 2; ++t3) {
                    int l3 = t3 ? 6 : 4;
                    for (int u3 = -l3; u3 <= l3; ++u3)
                        if (keepE(u1, u2, u3)) ++n;
                }
    }
    return n;
}
constexpr int NTOT = countEnt();
static_assert(NTOT > 0 && NTOT < 2048, "entry count sanity");

constexpr std::array<Ent, NTOT> makeTab() {
    std::array<Ent, NTOT> T{};
    int n = 0;
    // Order: (l1,l2) group-major, then u1,u2, then both l3 targets.
    // Keeps each x*y product's uses adjacent (register pressure control).
    for (int g = 0; g < 4; ++g) {
        int l1 = GRP[g][0], l2 = GRP[g][1];
        int xo = (l1 == 6) ? 9 : 0, yo = (l2 == 6) ? 9 : 0;
        for (int u1 = -l1; u1 <= l1; ++u1)
            for (int u2 = -l2; u2 <= l2; ++u2)
                for (int t3 = 0; t3 < 2; ++t3) {
                    int l3 = t3 ? 6 : 4;
                    int oo = (l3 == 6) ? 9 : 0;
                    for (int u3 = -l3; u3 <= l3; ++u3)
                        if (keepE(u1, u2, u3)) {
                            T[n].xi = (unsigned char)(xo + l1 + u1);
                            T[n].yi = (unsigned char)(yo + l2 + u2);
                            T[n].oi = (unsigned char)(oo + l3 + u3);
                            T[n].p  = (unsigned char)(((l1 == 6) ? 4 : 0) |
                                                      ((l2 == 6) ? 2 : 0) |
                                                      ((l3 == 6) ? 1 : 0));
                            ++n;
                        }
                }
    }
    return T;
}
constexpr auto TAB = makeTab();

constexpr std::array<double, 20> makeFact() {
    std::array<double, 20> F{};
    F[0] = 1.0;
    for (int i = 1; i < 20; ++i) F[i] = F[i - 1] * (double)i;
    return F;
}
constexpr auto FACT = makeFact();

// ---------------------------------------------------------------------------
// Init kernel: compute real-basis Wigner-3j values (fp64), Frobenius-normalize
// per path, bake in PW[p]*tp_weights[p], write compacted coefficients to d_ws.
// ---------------------------------------------------------------------------
DEV_INLINE double su2cg(int j1, int j2, int j3, int m1, int m2, int m3) {
    int vmin = -j1 + j2 + m3;
    if (-j1 + m1 > vmin) vmin = -j1 + m1;
    if (vmin < 0) vmin = 0;
    int vmax = j2 + j3 + m1;
    { int t = j3 - j1 + j2; if (t < vmax) vmax = t; t = j3 + m3; if (t < vmax) vmax = t; }
    double num = FACT[j3 + j1 - j2] * FACT[j3 - j1 + j2] * FACT[j1 + j2 - j3] *
                 FACT[j3 + m3] * FACT[j3 - m3];
    double den = FACT[j1 + j2 + j3 + 1] * FACT[j1 - m1] * FACT[j1 + m1] *
                 FACT[j2 - m2] * FACT[j2 + m2];
    double C = sqrt((2.0 * j3 + 1.0) * num / den);
    double S = 0.0;
    for (int v = vmin; v <= vmax; ++v) {
        double t = (FACT[j2 + j3 + m1 - v] * FACT[j1 - m1 + v]) /
                   (FACT[v] * FACT[j3 - j1 + j2 - v] * FACT[j3 + m3 - v] *
                    FACT[v + j1 - j2 - m3]);
        S += ((v + j2 + m2) & 1) ? -t : t;
    }
    return C * S;
}

struct Cplx { double re, im; };

// q (real->complex SH change of basis) WITHOUT the (-i)^l phase.
// Nonzero pattern: column j has nonzero rows {j, 2l-j}.
DEV_INLINE Cplx qent(int l, int r, int c) {
    const double s2 = 0.70710678118654752440;
    if (c == r) {
        if (r < l)  return {0.0, -s2};
        if (r == l) return {1.0, 0.0};
        return {((r - l) & 1) ? -s2 : s2, 0.0};
    }
    // c == 2l - r
    if (r < l) return {s2, 0.0};
    return {0.0, ((r - l) & 1) ? -s2 : s2};
}

DEV_INLINE double rawval(int e) {
    Ent E = TAB[e];
    int l1 = (E.p & 4) ? 6 : 4, l2 = (E.p & 2) ? 6 : 4, l3 = (E.p & 1) ? 6 : 4;
    int j = E.xi - ((l1 == 6) ? 9 : 0);
    int L = E.yi - ((l2 == 6) ? 9 : 0);
    int m = E.oi - ((l3 == 6) ? 9 : 0);
    double acc = 0.0;
    for (int a = 0; a < 2; ++a) {
        int i = a ? (2 * l1 - j) : j;
        if (a && i == j) continue;
        Cplx q1 = qent(l1, i, j);
        for (int b = 0; b < 2; ++b) {
            int k = b ? (2 * l2 - L) : L;
            if (b && k == L) continue;
            Cplx q2 = qent(l2, k, L);
            int m1 = i - l1, m2 = k - l2;
            int n = m1 + m2 + l3;                 // m3 = m1+m2 selection
            if (n < 0 || n > 2 * l3) continue;
            if (n != m && n != 2 * l3 - m) continue; // conj(q3) column-m support
            Cplx q3 = qent(l3, n, m);
            double cg = su2cg(l1, l2, l3, m1, m2, n - l3);
            double Ar = q1.re * q2.re - q1.im * q2.im;
            double Ai = q1.re * q2.im + q1.im * q2.re;
            acc += (Ar * q3.re + Ai * q3.im) * cg;  // Re(q1*q2*conj(q3))*cg
        }
    }
    // (-i)^l phases, real for even l: +1 (l=4), -1 (l=6)
    int s = 1;
    if (l1 == 6) s = -s;
    if (l2 == 6) s = -s;
    if (l3 == 6) s = -s;
    return s < 0 ? -acc : acc;
}

__global__ void init_cof_kernel(const float* __restrict__ tpw,
                                float* __restrict__ cof) {
    __shared__ double raw[NTOT];
    __shared__ double frob[8];
    for (int e = threadIdx.x; e < NTOT; e += blockDim.x)
        raw[e] = rawval(e);
    __syncthreads();
    if (threadIdx.x < 8) {
        double s = 0.0;
        for (int e = 0; e < NTOT; ++e)
            if (TAB[e].p == threadIdx.x) s += raw[e] * raw[e];
        frob[threadIdx.x] = sqrt(s);
    }
    __syncthreads();
    for (int e = threadIdx.x; e < NTOT; e += blockDim.x) {
        int p = TAB[e].p;
        int l3 = (p & 1) ? 6 : 4;
        double pw = 0.5 * sqrt(2.0 * l3 + 1.0);     // sqrt((2l3+1)/4)
        cof[e] = (float)(raw[e] * pw * (double)tpw[p] / frob[p]);
    }
}

// ---------------------------------------------------------------------------
// Main kernel: 64x4 tile/block (256 threads, 1 pos/thread).
// Stage (66x6)x22 halo tile in LDS channel-major; 3x3 conv; unrolled sparse TP.
// ---------------------------------------------------------------------------
__global__ void __launch_bounds__(256)
eq_conv_tp_kernel(const float* __restrict__ f4, const float* __restrict__ f6,
                  const float* __restrict__ sw, const float* __restrict__ cof,
                  float* __restrict__ dout) {
    __shared__ float ldsA[9][6][66];    // f4 channels
    __shared__ float ldsB[13][6][66];   // f6 channels
    const int tid = threadIdx.x;
    const int b  = blockIdx.x >> 10;            // 1024 tiles per batch
    const int t  = blockIdx.x & 1023;
    const int y0 = (t >> 3) * 4;                // 128 tile-rows
    const int x0 = (t & 7) * 64;                // 8 tile-cols

    const float* f4b = f4 + (size_t)b * (HWN * 9);
    const float* f6b = f6 + (size_t)b * (HWN * 13);

    for (int r = 0; r < 6; ++r) {
        int gy = y0 - 1 + r;
        gy = gy < 0 ? 0 : (gy > HH - 1 ? HH - 1 : gy);
        const float* row4 = f4b + gy * (WW * 9);
        const float* row6 = f6b + gy * (WW * 13);
        for (int idx = tid; idx < 66 * 9; idx += 256) {
            int i = idx / 9, c = idx - i * 9;
            int gx = x0 - 1 + i;
            gx = gx < 0 ? 0 : (gx > WW - 1 ? WW - 1 : gx);
            ldsA[c][r][i] = row4[gx * 9 + c];
        }
        for (int idx = tid; idx < 66 * 13; idx += 256) {
            int i = idx / 13, c = idx - i * 13;
            int gx = x0 - 1 + i;
            gx = gx < 0 ? 0 : (gx > WW - 1 ? WW - 1 : gx);
            ldsB[c][r][i] = row6[gx * 13 + c];
        }
    }
    __syncthreads();

    const int tx = tid & 63, ty = tid >> 6;

    float wv[9];
#pragma unroll
    for (int k = 0; k < 9; ++k) wv[k] = sw[k];   // wave-uniform -> SGPRs

    float xx[22], yy[22], oo[22];
#pragma unroll
    for (int c = 0; c < 9; ++c) {
        xx[c] = ldsA[c][ty + 1][tx + 1];
        float s = 0.f;
#pragma unroll
        for (int r = 0; r < 3; ++r)
#pragma unroll
            for (int d = 0; d < 3; ++d)
                s += wv[r * 3 + d] * ldsA[c][ty + r][tx + d];
        yy[c] = s;
    }
#pragma unroll
    for (int c = 0; c < 13; ++c) {
        xx[9 + c] = ldsB[c][ty + 1][tx + 1];
        float s = 0.f;
#pragma unroll
        for (int r = 0; r < 3; ++r)
#pragma unroll
            for (int d = 0; d < 3; ++d)
                s += wv[r * 3 + d] * ldsB[c][ty + r][tx + d];
        yy[9 + c] = s;
    }

    // residual init
#pragma unroll
    for (int c = 0; c < 22; ++c) oo[c] = xx[c];

    // sparse tensor product, fully unrolled; TAB[e] folds to immediates,
    // cof[e] are wave-uniform scalar loads.
#pragma unroll
    for (int e = 0; e < NTOT; ++e) {
        const int xi = TAB[e].xi, yi = TAB[e].yi, oi = TAB[e].oi;
        float pr = xx[xi] * yy[yi];     // CSE'd across the (<=4) users
        oo[oi] += cof[e] * pr;
    }

    const int pos = b * HWN + (y0 + ty) * WW + (x0 + tx);
    float* o4 = dout + (size_t)pos * 9;
    float* o6 = dout + OUT1OFF + (size_t)pos * 13;
#pragma unroll
    for (int c = 0; c < 9; ++c)  o4[c] = oo[c];
#pragma unroll
    for (int c = 0; c < 13; ++c) o6[c] = oo[9 + c];
}

extern "C" void kernel_launch(void* const* d_in, const int* in_sizes, int n_in,
                              void* d_out, int out_size, void* d_ws, size_t ws_size,
                              hipStream_t stream) {
    const float* f4  = (const float*)d_in[0];
    const float* f6  = (const float*)d_in[1];
    const float* sw  = (const float*)d_in[2];
    const float* tpw = (const float*)d_in[3];
    float* cof = (float*)d_ws;          // NTOT floats of scratch
    float* out = (float*)d_out;

    hipLaunchKernelGGL(init_cof_kernel, dim3(1), dim3(256), 0, stream, tpw, cof);
    hipLaunchKernelGGL(eq_conv_tp_kernel,
                       dim3(BB * (HH / 4) * (WW / 64)), dim3(256), 0, stream,
                       f4, f6, sw, cof, out);
}

// Round 2
// 707.704 us; speedup vs baseline: 2.4018x; 2.4018x over previous
//
#include <hip/hip_runtime.h>
#include <array>

#define DEV_INLINE __device__ __forceinline__

// Problem geometry (fixed by setup_inputs)
constexpr int HH = 512, WW = 512, BB = 4;
constexpr int HWN = HH * WW;
constexpr int OUT1OFF = BB * HWN * 9;   // d_out: [B*HW*9] then [B*HW*13]

// ---------------------------------------------------------------------------
// Compile-time sparse structure of the real Wigner-3j tensors.
// Support rule (exact): |u3| in {|u1|+|u2|, ||u1|-|u2||} and an even number of
// negative (sin-type) indices.
// ---------------------------------------------------------------------------
constexpr bool keepE(int u1, int u2, int u3) {
    int a = u1 < 0 ? -u1 : u1, b = u2 < 0 ? -u2 : u2, c = u3 < 0 ? -u3 : u3;
    int neg = (u1 < 0) + (u2 < 0) + (u3 < 0);
    if (neg & 1) return false;
    int d = a > b ? a - b : b - a;
    return (c == a + b) || (c == d);
}

struct Ent { unsigned char xi, yi, oi, p; };

constexpr int GRP[4][2] = {{4,4},{4,6},{6,4},{6,6}};

constexpr int countEnt() {
    int n = 0;
    for (int g = 0; g < 4; ++g) {
        int l1 = GRP[g][0], l2 = GRP[g][1];
        for (int u1 = -l1; u1 <= l1; ++u1)
            for (int u2 = -l2; u2 <= l2; ++u2)
                for (int t3 = 0; t3 < 2; ++t3) {
                    int l3 = t3 ? 6 : 4;
                    for (int u3 = -l3; u3 <= l3; ++u3)
                        if (keepE(u1, u2, u3)) ++n;
                }
    }
    return n;
}
constexpr int NTOT = countEnt();
static_assert(NTOT > 0 && NTOT < 4096, "entry count sanity");

constexpr std::array<Ent, NTOT> makeTab() {
    std::array<Ent, NTOT> T{};
    int n = 0;
    // Order: (l1,l2) group-major, then u1,u2, then both l3 targets.
    // All entries sharing one x*y product are adjacent.
    for (int g = 0; g < 4; ++g) {
        int l1 = GRP[g][0], l2 = GRP[g][1];
        int xo = (l1 == 6) ? 9 : 0, yo = (l2 == 6) ? 9 : 0;
        for (int u1 = -l1; u1 <= l1; ++u1)
            for (int u2 = -l2; u2 <= l2; ++u2)
                for (int t3 = 0; t3 < 2; ++t3) {
                    int l3 = t3 ? 6 : 4;
                    int oo = (l3 == 6) ? 9 : 0;
                    for (int u3 = -l3; u3 <= l3; ++u3)
                        if (keepE(u1, u2, u3)) {
                            T[n].xi = (unsigned char)(xo + l1 + u1);
                            T[n].yi = (unsigned char)(yo + l2 + u2);
                            T[n].oi = (unsigned char)(oo + l3 + u3);
                            T[n].p  = (unsigned char)(((l1 == 6) ? 4 : 0) |
                                                      ((l2 == 6) ? 2 : 0) |
                                                      ((l3 == 6) ? 1 : 0));
                            ++n;
                        }
                }
    }
    return T;
}
constexpr auto TAB = makeTab();

// Group entries into runs sharing one (xi,yi) product (<=4 entries per run).
struct Run { unsigned short e0; unsigned char xi, yi, n; };

constexpr int countRuns() {
    int n = 0;
    for (int e = 0; e < NTOT; ) {
        int j = e;
        while (j < NTOT && TAB[j].xi == TAB[e].xi && TAB[j].yi == TAB[e].yi) ++j;
        ++n; e = j;
    }
    return n;
}
constexpr int NRUN = countRuns();

constexpr std::array<Run, NRUN> makeRuns() {
    std::array<Run, NRUN> R{};
    int n = 0;
    for (int e = 0; e < NTOT; ) {
        int j = e;
        while (j < NTOT && TAB[j].xi == TAB[e].xi && TAB[j].yi == TAB[e].yi) ++j;
        R[n].e0 = (unsigned short)e;
        R[n].xi = TAB[e].xi;
        R[n].yi = TAB[e].yi;
        R[n].n  = (unsigned char)(j - e);
        ++n; e = j;
    }
    return R;
}
constexpr auto RUNS = makeRuns();

constexpr std::array<double, 20> makeFact() {
    std::array<double, 20> F{};
    F[0] = 1.0;
    for (int i = 1; i < 20; ++i) F[i] = F[i - 1] * (double)i;
    return F;
}
constexpr auto FACT = makeFact();

// ---------------------------------------------------------------------------
// Init kernel: real-basis Wigner-3j values (fp64), Frobenius-normalize per
// path, bake in PW[p]*tp_weights[p], write compacted coefficients to d_ws.
// ---------------------------------------------------------------------------
DEV_INLINE double su2cg(int j1, int j2, int j3, int m1, int m2, int m3) {
    int vmin = -j1 + j2 + m3;
    if (-j1 + m1 > vmin) vmin = -j1 + m1;
    if (vmin < 0) vmin = 0;
    int vmax = j2 + j3 + m1;
    { int t = j3 - j1 + j2; if (t < vmax) vmax = t; t = j3 + m3; if (t < vmax) vmax = t; }
    double num = FACT[j3 + j1 - j2] * FACT[j3 - j1 + j2] * FACT[j1 + j2 - j3] *
                 FACT[j3 + m3] * FACT[j3 - m3];
    double den = FACT[j1 + j2 + j3 + 1] * FACT[j1 - m1] * FACT[j1 + m1] *
                 FACT[j2 - m2] * FACT[j2 + m2];
    double C = sqrt((2.0 * j3 + 1.0) * num / den);
    double S = 0.0;
    for (int v = vmin; v <= vmax; ++v) {
        double t = (FACT[j2 + j3 + m1 - v] * FACT[j1 - m1 + v]) /
                   (FACT[v] * FACT[j3 - j1 + j2 - v] * FACT[j3 + m3 - v] *
                    FACT[v + j1 - j2 - m3]);
        S += ((v + j2 + m2) & 1) ? -t : t;
    }
    return C * S;
}

struct Cplx { double re, im; };

// q (real->complex SH change of basis) WITHOUT the (-i)^l phase.
// Nonzero pattern: column j has nonzero rows {j, 2l-j}.
DEV_INLINE Cplx qent(int l, int r, int c) {
    const double s2 = 0.70710678118654752440;
    if (c == r) {
        if (r < l)  return {0.0, -s2};
        if (r == l) return {1.0, 0.0};
        return {((r - l) & 1) ? -s2 : s2, 0.0};
    }
    // c == 2l - r
    if (r < l) return {s2, 0.0};
    return {0.0, ((r - l) & 1) ? -s2 : s2};
}

DEV_INLINE double rawval(int e) {
    Ent E = TAB[e];
    int l1 = (E.p & 4) ? 6 : 4, l2 = (E.p & 2) ? 6 : 4, l3 = (E.p & 1) ? 6 : 4;
    int j = E.xi - ((l1 == 6) ? 9 : 0);
    int L = E.yi - ((l2 == 6) ? 9 : 0);
    int m = E.oi - ((l3 == 6) ? 9 : 0);
    double acc = 0.0;
    for (int a = 0; a < 2; ++a) {
        int i = a ? (2 * l1 - j) : j;
        if (a && i == j) continue;
        Cplx q1 = qent(l1, i, j);
        for (int b = 0; b < 2; ++b) {
            int k = b ? (2 * l2 - L) : L;
            if (b && k == L) continue;
            Cplx q2 = qent(l2, k, L);
            int m1 = i - l1, m2 = k - l2;
            int n = m1 + m2 + l3;                 // m3 = m1+m2 selection
            if (n < 0 || n > 2 * l3) continue;
            if (n != m && n != 2 * l3 - m) continue; // conj(q3) column-m support
            Cplx q3 = qent(l3, n, m);
            double cg = su2cg(l1, l2, l3, m1, m2, n - l3);
            double Ar = q1.re * q2.re - q1.im * q2.im;
            double Ai = q1.re * q2.im + q1.im * q2.re;
            acc += (Ar * q3.re + Ai * q3.im) * cg;  // Re(q1*q2*conj(q3))*cg
        }
    }
    // (-i)^l phases, real for even l: +1 (l=4), -1 (l=6)
    int s = 1;
    if (l1 == 6) s = -s;
    if (l2 == 6) s = -s;
    if (l3 == 6) s = -s;
    return s < 0 ? -acc : acc;
}

__global__ void init_cof_kernel(const float* __restrict__ tpw,
                                float* __restrict__ cof) {
    __shared__ double raw[NTOT];
    __shared__ double frob[8];
    for (int e = threadIdx.x; e < NTOT; e += blockDim.x)
        raw[e] = rawval(e);
    __syncthreads();
    if (threadIdx.x < 8) {
        double s = 0.0;
        for (int e = 0; e < NTOT; ++e)
            if (TAB[e].p == threadIdx.x) s += raw[e] * raw[e];
        frob[threadIdx.x] = sqrt(s);
    }
    __syncthreads();
    for (int e = threadIdx.x; e < NTOT; e += blockDim.x) {
        int p = TAB[e].p;
        int l3 = (p & 1) ? 6 : 4;
        double pw = 0.5 * sqrt(2.0 * l3 + 1.0);     // sqrt((2l3+1)/4)
        cof[e] = (float)(raw[e] * pw * (double)tpw[p] / frob[p]);
    }
}

// ---------------------------------------------------------------------------
// Force-unrolled TP: divide-and-conquer templates so EVERY xx/yy/oo index is
// a compile-time constant (no scratch demotion — rule #20).
// ---------------------------------------------------------------------------
template<int E, int N>
struct AccChain {
    static DEV_INLINE void run(const float* __restrict__ cof, float pr,
                               float (&oo)[22]) {
        constexpr int oi = TAB[E].oi;
        oo[oi] = fmaf(cof[E], pr, oo[oi]);
        if constexpr (N > 1) AccChain<E + 1, N - 1>::run(cof, pr, oo);
    }
};

template<int LO, int HI>
struct TPR {
    static DEV_INLINE void run(const float* __restrict__ cof,
                               const float (&xx)[22], const float (&yy)[22],
                               float (&oo)[22]) {
        if constexpr (HI - LO == 1) {
            constexpr Run R = RUNS[LO];
            float pr = xx[R.xi] * yy[R.yi];
            AccChain<R.e0, R.n>::run(cof, pr, oo);
        } else {
            constexpr int MID = LO + (HI - LO) / 2;
            TPR<LO, MID>::run(cof, xx, yy, oo);
            TPR<MID, HI>::run(cof, xx, yy, oo);
        }
    }
};

// ---------------------------------------------------------------------------
// Main kernel: 64x4 tile/block (256 threads, 1 pos/thread).
// Stage (66x6)x22 halo tile in LDS channel-major; 3x3 conv; unrolled sparse TP.
// ---------------------------------------------------------------------------
__global__ void __launch_bounds__(256)
eq_conv_tp_kernel(const float* __restrict__ f4, const float* __restrict__ f6,
                  const float* __restrict__ sw, const float* __restrict__ cof,
                  float* __restrict__ dout) {
    __shared__ float ldsA[9][6][66];    // f4 channels
    __shared__ float ldsB[13][6][66];   // f6 channels
    const int tid = threadIdx.x;
    const int b  = blockIdx.x >> 10;            // 1024 tiles per batch
    const int t  = blockIdx.x & 1023;
    const int y0 = (t >> 3) * 4;                // 128 tile-rows
    const int x0 = (t & 7) * 64;                // 8 tile-cols

    const float* f4b = f4 + (size_t)b * (HWN * 9);
    const float* f6b = f6 + (size_t)b * (HWN * 13);

    for (int r = 0; r < 6; ++r) {
        int gy = y0 - 1 + r;
        gy = gy < 0 ? 0 : (gy > HH - 1 ? HH - 1 : gy);
        const float* row4 = f4b + gy * (WW * 9);
        const float* row6 = f6b + gy * (WW * 13);
        for (int idx = tid; idx < 66 * 9; idx += 256) {
            int i = idx / 9, c = idx - i * 9;
            int gx = x0 - 1 + i;
            gx = gx < 0 ? 0 : (gx > WW - 1 ? WW - 1 : gx);
            ldsA[c][r][i] = row4[gx * 9 + c];
        }
        for (int idx = tid; idx < 66 * 13; idx += 256) {
            int i = idx / 13, c = idx - i * 13;
            int gx = x0 - 1 + i;
            gx = gx < 0 ? 0 : (gx > WW - 1 ? WW - 1 : gx);
            ldsB[c][r][i] = row6[gx * 13 + c];
        }
    }
    __syncthreads();

    const int tx = tid & 63, ty = tid >> 6;

    float wv[9];
#pragma unroll
    for (int k = 0; k < 9; ++k) wv[k] = sw[k];   // wave-uniform -> SGPRs

    float xx[22], yy[22], oo[22];
#pragma unroll
    for (int c = 0; c < 9; ++c) {
        xx[c] = ldsA[c][ty + 1][tx + 1];
        float s = 0.f;
#pragma unroll
        for (int r = 0; r < 3; ++r)
#pragma unroll
            for (int d = 0; d < 3; ++d)
                s = fmaf(wv[r * 3 + d], ldsA[c][ty + r][tx + d], s);
        yy[c] = s;
    }
#pragma unroll
    for (int c = 0; c < 13; ++c) {
        xx[9 + c] = ldsB[c][ty + 1][tx + 1];
        float s = 0.f;
#pragma unroll
        for (int r = 0; r < 3; ++r)
#pragma unroll
            for (int d = 0; d < 3; ++d)
                s = fmaf(wv[r * 3 + d], ldsB[c][ty + r][tx + d], s);
        yy[9 + c] = s;
    }

    // residual init
#pragma unroll
    for (int c = 0; c < 22; ++c) oo[c] = xx[c];

    // sparse tensor product — template-forced full unroll
    TPR<0, NRUN>::run(cof, xx, yy, oo);

    const int pos = b * HWN + (y0 + ty) * WW + (x0 + tx);
    float* o4 = dout + (size_t)pos * 9;
    float* o6 = dout + OUT1OFF + (size_t)pos * 13;
#pragma unroll
    for (int c = 0; c < 9; ++c)  o4[c] = oo[c];
#pragma unroll
    for (int c = 0; c < 13; ++c) o6[c] = oo[9 + c];
}

extern "C" void kernel_launch(void* const* d_in, const int* in_sizes, int n_in,
                              void* d_out, int out_size, void* d_ws, size_t ws_size,
                              hipStream_t stream) {
    const float* f4  = (const float*)d_in[0];
    const float* f6  = (const float*)d_in[1];
    const float* sw  = (const float*)d_in[2];
    const float* tpw = (const float*)d_in[3];
    float* cof = (float*)d_ws;          // NTOT floats of scratch
    float* out = (float*)d_out;

    hipLaunchKernelGGL(init_cof_kernel, dim3(1), dim3(256), 0, stream, tpw, cof);
    hipLaunchKernelGGL(eq_conv_tp_kernel,
                       dim3(BB * (HH / 4) * (WW / 64)), dim3(256), 0, stream,
                       f4, f6, sw, cof, out);
}

// Round 3
// 292.816 us; speedup vs baseline: 5.8049x; 2.4169x over previous
//
#include <hip/hip_runtime.h>
#include <array>

#define DEV_INLINE __device__ __forceinline__

// Problem geometry (fixed by setup_inputs)
constexpr int HH = 512, WW = 512, BB = 4;
constexpr int HWN = HH * WW;
constexpr int OUT1OFF = BB * HWN * 9;   // d_out: [B*HW*9] then [B*HW*13]

// ---------------------------------------------------------------------------
// Compile-time sparse structure of the real Wigner-3j tensors.
// Support rule (exact): |u3| in {|u1|+|u2|, ||u1|-|u2||} and an even number of
// negative (sin-type) indices.
// ---------------------------------------------------------------------------
constexpr bool keepE(int u1, int u2, int u3) {
    int a = u1 < 0 ? -u1 : u1, b = u2 < 0 ? -u2 : u2, c = u3 < 0 ? -u3 : u3;
    int neg = (u1 < 0) + (u2 < 0) + (u3 < 0);
    if (neg & 1) return false;
    int d = a > b ? a - b : b - a;
    return (c == a + b) || (c == d);
}

struct Ent { unsigned char xi, yi, oi, p; };

constexpr int GRP[4][2] = {{4,4},{4,6},{6,4},{6,6}};

constexpr int countEnt() {
    int n = 0;
    for (int g = 0; g < 4; ++g) {
        int l1 = GRP[g][0], l2 = GRP[g][1];
        for (int u1 = -l1; u1 <= l1; ++u1)
            for (int u2 = -l2; u2 <= l2; ++u2)
                for (int t3 = 0; t3 < 2; ++t3) {
                    int l3 = t3 ? 6 : 4;
                    for (int u3 = -l3; u3 <= l3; ++u3)
                        if (keepE(u1, u2, u3)) ++n;
                }
    }
    return n;
}
constexpr int NTOT = countEnt();
static_assert(NTOT > 0 && NTOT < 4096, "entry count sanity");

constexpr std::array<Ent, NTOT> makeTab() {
    std::array<Ent, NTOT> T{};
    int n = 0;
    // (l1,l2) group-major, then u1,u2, then l3=4 entries before l3=6.
    for (int g = 0; g < 4; ++g) {
        int l1 = GRP[g][0], l2 = GRP[g][1];
        int xo = (l1 == 6) ? 9 : 0, yo = (l2 == 6) ? 9 : 0;
        for (int u1 = -l1; u1 <= l1; ++u1)
            for (int u2 = -l2; u2 <= l2; ++u2)
                for (int t3 = 0; t3 < 2; ++t3) {
                    int l3 = t3 ? 6 : 4;
                    int oo = (l3 == 6) ? 9 : 0;
                    for (int u3 = -l3; u3 <= l3; ++u3)
                        if (keepE(u1, u2, u3)) {
                            T[n].xi = (unsigned char)(xo + l1 + u1);
                            T[n].yi = (unsigned char)(yo + l2 + u2);
                            T[n].oi = (unsigned char)(oo + l3 + u3);
                            T[n].p  = (unsigned char)(((l1 == 6) ? 4 : 0) |
                                                      ((l2 == 6) ? 2 : 0) |
                                                      ((l3 == 6) ? 1 : 0));
                            ++n;
                        }
                }
    }
    return T;
}
constexpr auto TAB = makeTab();

// Group entries into runs sharing one (xi,yi) product.
struct Run { unsigned short e0; unsigned char xi, yi, n; };

constexpr int countRuns() {
    int n = 0;
    for (int e = 0; e < NTOT; ) {
        int j = e;
        while (j < NTOT && TAB[j].xi == TAB[e].xi && TAB[j].yi == TAB[e].yi) ++j;
        ++n; e = j;
    }
    return n;
}
constexpr int NRUN = countRuns();

constexpr std::array<Run, NRUN> makeRuns() {
    std::array<Run, NRUN> R{};
    int n = 0;
    for (int e = 0; e < NTOT; ) {
        int j = e;
        while (j < NTOT && TAB[j].xi == TAB[e].xi && TAB[j].yi == TAB[e].yi) ++j;
        R[n].e0 = (unsigned short)e;
        R[n].xi = TAB[e].xi;
        R[n].yi = TAB[e].yi;
        R[n].n  = (unsigned char)(j - e);
        ++n; e = j;
    }
    return R;
}
constexpr auto RUNS = makeRuns();

// ---------------------------------------------------------------------------
// Compile-time Wigner-3j values (fp64 constexpr, Newton csqrt).
// ---------------------------------------------------------------------------
constexpr std::array<double, 20> makeFact() {
    std::array<double, 20> F{};
    F[0] = 1.0;
    for (int i = 1; i < 20; ++i) F[i] = F[i - 1] * (double)i;
    return F;
}
constexpr auto FACT = makeFact();

constexpr double csqrt(double x) {
    if (x <= 0.0) return 0.0;
    double g = x > 1.0 ? x : 1.0, prev = 0.0;
    for (int i = 0; i < 200 && g != prev; ++i) { prev = g; g = 0.5 * (g + x / g); }
    return g;
}

constexpr double su2cg(int j1, int j2, int j3, int m1, int m2, int m3) {
    int vmin = -j1 + j2 + m3;
    if (-j1 + m1 > vmin) vmin = -j1 + m1;
    if (vmin < 0) vmin = 0;
    int vmax = j2 + j3 + m1;
    { int t = j3 - j1 + j2; if (t < vmax) vmax = t; t = j3 + m3; if (t < vmax) vmax = t; }
    double num = FACT[j3 + j1 - j2] * FACT[j3 - j1 + j2] * FACT[j1 + j2 - j3] *
                 FACT[j3 + m3] * FACT[j3 - m3];
    double den = FACT[j1 + j2 + j3 + 1] * FACT[j1 - m1] * FACT[j1 + m1] *
                 FACT[j2 - m2] * FACT[j2 + m2];
    double C = csqrt((2.0 * j3 + 1.0) * num / den);
    double S = 0.0;
    for (int v = vmin; v <= vmax; ++v) {
        double t = (FACT[j2 + j3 + m1 - v] * FACT[j1 - m1 + v]) /
                   (FACT[v] * FACT[j3 - j1 + j2 - v] * FACT[j3 + m3 - v] *
                    FACT[v + j1 - j2 - m3]);
        S += ((v + j2 + m2) & 1) ? -t : t;
    }
    return C * S;
}

struct Cplx { double re, im; };

// q (real->complex SH change of basis) WITHOUT the (-i)^l phase.
// Column j has nonzero rows {j, 2l-j}.
constexpr Cplx qent(int l, int r, int c) {
    const double s2 = 0.70710678118654752440;
    if (c == r) {
        if (r < l)  return {0.0, -s2};
        if (r == l) return {1.0, 0.0};
        return {((r - l) & 1) ? -s2 : s2, 0.0};
    }
    if (r < l) return {s2, 0.0};
    return {0.0, ((r - l) & 1) ? -s2 : s2};
}

constexpr double rawval(int e) {
    Ent E = TAB[e];
    int l1 = (E.p & 4) ? 6 : 4, l2 = (E.p & 2) ? 6 : 4, l3 = (E.p & 1) ? 6 : 4;
    int j = E.xi - ((l1 == 6) ? 9 : 0);
    int L = E.yi - ((l2 == 6) ? 9 : 0);
    int m = E.oi - ((l3 == 6) ? 9 : 0);
    double acc = 0.0;
    for (int a = 0; a < 2; ++a) {
        int i = a ? (2 * l1 - j) : j;
        if (a && i == j) continue;
        Cplx q1 = qent(l1, i, j);
        for (int b = 0; b < 2; ++b) {
            int k = b ? (2 * l2 - L) : L;
            if (b && k == L) continue;
            Cplx q2 = qent(l2, k, L);
            int m1 = i - l1, m2 = k - l2;
            int n = m1 + m2 + l3;
            if (n < 0 || n > 2 * l3) continue;
            if (n != m && n != 2 * l3 - m) continue;
            Cplx q3 = qent(l3, n, m);
            double cg = su2cg(l1, l2, l3, m1, m2, n - l3);
            double Ar = q1.re * q2.re - q1.im * q2.im;
            double Ai = q1.re * q2.im + q1.im * q2.re;
            acc += (Ar * q3.re + Ai * q3.im) * cg;
        }
    }
    int s = 1;                       // (-i)^l phases, real for even l
    if (l1 == 6) s = -s;
    if (l2 == 6) s = -s;
    if (l3 == 6) s = -s;
    return s < 0 ? -acc : acc;
}

// Frobenius norms per path — chunked into separate top-level constexpr
// evaluations to stay under the per-expression constexpr step limit.
constexpr int NCH = 16;
constexpr int CHSZ = (NTOT + NCH - 1) / NCH;

template<int C>
constexpr std::array<double, 8> frobChunk() {
    std::array<double, 8> s{};
    for (int i = 0; i < CHSZ; ++i) {
        int e = C * CHSZ + i;
        if (e < NTOT) { double r = rawval(e); s[TAB[e].p] += r * r; }
    }
    return s;
}
constexpr auto FR0  = frobChunk<0>();   constexpr auto FR1  = frobChunk<1>();
constexpr auto FR2  = frobChunk<2>();   constexpr auto FR3  = frobChunk<3>();
constexpr auto FR4  = frobChunk<4>();   constexpr auto FR5  = frobChunk<5>();
constexpr auto FR6  = frobChunk<6>();   constexpr auto FR7  = frobChunk<7>();
constexpr auto FR8  = frobChunk<8>();   constexpr auto FR9  = frobChunk<9>();
constexpr auto FR10 = frobChunk<10>();  constexpr auto FR11 = frobChunk<11>();
constexpr auto FR12 = frobChunk<12>();  constexpr auto FR13 = frobChunk<13>();
constexpr auto FR14 = frobChunk<14>();  constexpr auto FR15 = frobChunk<15>();

constexpr std::array<double, 8> makeFrob() {
    std::array<double, 8> s{};
    const std::array<double, 8>* parts[NCH] = {
        &FR0,&FR1,&FR2,&FR3,&FR4,&FR5,&FR6,&FR7,
        &FR8,&FR9,&FR10,&FR11,&FR12,&FR13,&FR14,&FR15};
    for (int c = 0; c < NCH; ++c)
        for (int p = 0; p < 8; ++p) s[p] += (*parts[c])[p];
    for (int p = 0; p < 8; ++p) s[p] = csqrt(s[p]);
    return s;
}
constexpr auto FROB = makeFrob();

// Per-entry final coefficient (w3j * pw / frob) — evaluated per template
// instantiation (own constexpr budget), emitted as a 32-bit inline literal.
template<int E>
struct CofV {
    static constexpr int    P  = TAB[E].p;
    static constexpr double PW = 0.5 * ((P & 1) ? 3.60555127546398929312 /*sqrt13*/
                                               : 3.0 /*sqrt9*/);
    static constexpr float  v  = (float)(rawval(E) * PW / FROB[P]);
};

// ---------------------------------------------------------------------------
// Force-unrolled TP — every index compile-time constant, every coefficient an
// inline literal; tpw[p] scaling via SGPR-resident scalars.
// ---------------------------------------------------------------------------
template<int E, int N>
struct AccChain {
    static DEV_INLINE void run(float pr4, float pr6, float (&oo)[22]) {
        constexpr int oi = TAB[E].oi;
        constexpr float kc = CofV<E>::v;
        oo[oi] = fmaf(kc, (TAB[E].p & 1) ? pr6 : pr4, oo[oi]);
        if constexpr (N > 1) AccChain<E + 1, N - 1>::run(pr4, pr6, oo);
    }
};

template<int LO, int HI>
struct TPR {
    static DEV_INLINE void run(const float (&tpws)[8],
                               const float (&xx)[22], const float (&yy)[22],
                               float (&oo)[22]) {
        if constexpr (HI - LO == 1) {
            constexpr Run R = RUNS[LO];
            constexpr int pb   = TAB[R.e0].p & 6;
            constexpr bool has4 = (TAB[R.e0].p & 1) == 0;
            constexpr bool has6 = (TAB[R.e0 + R.n - 1].p & 1) == 1;
            float pr = xx[R.xi] * yy[R.yi];
            float pr4 = 0.f, pr6 = 0.f;
            if constexpr (has4) pr4 = pr * tpws[pb];
            if constexpr (has6) pr6 = pr * tpws[pb | 1];
            AccChain<R.e0, R.n>::run(pr4, pr6, oo);
        } else {
            constexpr int MID = LO + (HI - LO) / 2;
            TPR<LO, MID>::run(tpws, xx, yy, oo);
            TPR<MID, HI>::run(tpws, xx, yy, oo);
        }
    }
};

// ---------------------------------------------------------------------------
// Main kernel: 64x4 tile/block (256 threads, 1 pos/thread).
// ---------------------------------------------------------------------------
__global__ void __launch_bounds__(256)
eq_conv_tp_kernel(const float* __restrict__ f4, const float* __restrict__ f6,
                  const float* __restrict__ sw, const float* __restrict__ tpw,
                  float* __restrict__ dout) {
    __shared__ float ldsA[9][6][66];    // f4 channels
    __shared__ float ldsB[13][6][66];   // f6 channels
    const int tid = threadIdx.x;
    const int b  = blockIdx.x >> 10;            // 1024 tiles per batch
    const int t  = blockIdx.x & 1023;
    const int y0 = (t >> 3) * 4;                // 128 tile-rows
    const int x0 = (t & 7) * 64;                // 8 tile-cols

    const float* f4b = f4 + (size_t)b * (HWN * 9);
    const float* f6b = f6 + (size_t)b * (HWN * 13);

    // wave-uniform weights -> SGPRs (issued before staging to overlap)
    float wv[9];
#pragma unroll
    for (int k = 0; k < 9; ++k) wv[k] = sw[k];
    float tpws[8];
#pragma unroll
    for (int k = 0; k < 8; ++k) tpws[k] = tpw[k];

    for (int r = 0; r < 6; ++r) {
        int gy = y0 - 1 + r;
        gy = gy < 0 ? 0 : (gy > HH - 1 ? HH - 1 : gy);
        const float* row4 = f4b + gy * (WW * 9);
        const float* row6 = f6b + gy * (WW * 13);
        for (int idx = tid; idx < 66 * 9; idx += 256) {
            int i = idx / 9, c = idx - i * 9;
            int gx = x0 - 1 + i;
            gx = gx < 0 ? 0 : (gx > WW - 1 ? WW - 1 : gx);
            ldsA[c][r][i] = row4[gx * 9 + c];
        }
        for (int idx = tid; idx < 66 * 13; idx += 256) {
            int i = idx / 13, c = idx - i * 13;
            int gx = x0 - 1 + i;
            gx = gx < 0 ? 0 : (gx > WW - 1 ? WW - 1 : gx);
            ldsB[c][r][i] = row6[gx * 13 + c];
        }
    }
    __syncthreads();

    const int tx = tid & 63, ty = tid >> 6;

    float xx[22], yy[22], oo[22];
#pragma unroll
    for (int c = 0; c < 9; ++c) {
        xx[c] = ldsA[c][ty + 1][tx + 1];
        float s = 0.f;
#pragma unroll
        for (int r = 0; r < 3; ++r)
#pragma unroll
            for (int d = 0; d < 3; ++d)
                s = fmaf(wv[r * 3 + d], ldsA[c][ty + r][tx + d], s);
        yy[c] = s;
    }
#pragma unroll
    for (int c = 0; c < 13; ++c) {
        xx[9 + c] = ldsB[c][ty + 1][tx + 1];
        float s = 0.f;
#pragma unroll
        for (int r = 0; r < 3; ++r)
#pragma unroll
            for (int d = 0; d < 3; ++d)
                s = fmaf(wv[r * 3 + d], ldsB[c][ty + r][tx + d], s);
        yy[9 + c] = s;
    }

    // residual init
#pragma unroll
    for (int c = 0; c < 22; ++c) oo[c] = xx[c];

    // sparse tensor product — literal coefficients, no loads
    TPR<0, NRUN>::run(tpws, xx, yy, oo);

    const int pos = b * HWN + (y0 + ty) * WW + (x0 + tx);
    float* o4 = dout + (size_t)pos * 9;
    float* o6 = dout + OUT1OFF + (size_t)pos * 13;
#pragma unroll
    for (int c = 0; c < 9; ++c)  o4[c] = oo[c];
#pragma unroll
    for (int c = 0; c < 13; ++c) o6[c] = oo[9 + c];
}

extern "C" void kernel_launch(void* const* d_in, const int* in_sizes, int n_in,
                              void* d_out, int out_size, void* d_ws, size_t ws_size,
                              hipStream_t stream) {
    const float* f4  = (const float*)d_in[0];
    const float* f6  = (const float*)d_in[1];
    const float* sw  = (const float*)d_in[2];
    const float* tpw = (const float*)d_in[3];
    float* out = (float*)d_out;

    hipLaunchKernelGGL(eq_conv_tp_kernel,
                       dim3(BB * (HH / 4) * (WW / 64)), dim3(256), 0, stream,
                       f4, f6, sw, tpw, out);
}